// Round 7
// baseline (2973.935 us; speedup 1.0000x reference)
//
#include <hip/hip_runtime.h>
#include <hip/hip_bf16.h>

#define SEQ   2048
#define DIM   300
#define UU    150
#define G4    600   // 4*U
#define H1    300
#define NSYN  4
#define NGRP  19    // ceil(76 pairs / 4); group = 4 f16-pairs = u32x4
#define NLDS  16    // groups resident in LDS (64 pairs, 150 KiB)

typedef _Float16 half2v __attribute__((ext_vector_type(2)));
typedef unsigned u32x4 __attribute__((ext_vector_type(4)));
union HU { unsigned u; half2v h; };

static __device__ __forceinline__ float sigm(float x) { return 1.0f / (1.0f + __expf(-x)); }
static __device__ __forceinline__ float tanh_fast(float x) { return 1.0f - 2.0f / (1.0f + __expf(2.0f * x)); }

// HW dot2: acc += w.x*h.x + w.y*h.y (f16 pairs, f32 accumulate). Both operands VGPR.
static __device__ __forceinline__ float dot2v(unsigned w, unsigned h, float acc) {
    asm("v_dot2_f32_f16 %0, %1, %2, %0" : "+v"(acc) : "v"(w), "v"(h));
    return acc;
}

// LDS-only barrier: drains lgkmcnt (LDS) but NOT vmcnt (fire-and-forget global stores).
#define LDS_BARRIER() asm volatile("s_waitcnt lgkmcnt(0)\n\ts_barrier" ::: "memory")

// ---------------------------------------------------------------------------
// Kernel A: emb = embedding[sentence];  Xpre_dir = emb @ Wk_dir + b_dir
// ---------------------------------------------------------------------------
__global__ void xpre_kernel(const int* __restrict__ sentence,
                            const float* __restrict__ emb_mat,
                            const float* __restrict__ Wk_f,
                            const float* __restrict__ b_f,
                            const float* __restrict__ Wk_b,
                            const float* __restrict__ b_b,
                            float* __restrict__ Xf, float* __restrict__ Xb)
{
    const int dir = blockIdx.y;
    const float* Wk = dir ? Wk_b : Wk_f;
    const float* bb = dir ? b_b : b_f;
    float* X = dir ? Xb : Xf;

    const int s0  = blockIdx.x * 8;
    const int tid = threadIdx.x;

    __shared__ int   sids[8];
    __shared__ float embs[8][DIM];

    if (tid < 8) sids[tid] = sentence[s0 + tid];
    __syncthreads();
    for (int e = tid; e < 8 * DIM; e += 640) {
        int r = e / DIM, d = e - r * DIM;
        embs[r][d] = emb_mat[(long)sids[r] * DIM + d];
    }
    __syncthreads();

    if (tid < G4) {
        float acc[8];
        float bv = bb[tid];
        #pragma unroll
        for (int r = 0; r < 8; ++r) acc[r] = bv;
        for (int k = 0; k < DIM; ++k) {
            float wv = Wk[k * G4 + tid];
            #pragma unroll
            for (int r = 0; r < 8; ++r) acc[r] = fmaf(embs[r][k], wv, acc[r]);
        }
        #pragma unroll
        for (int r = 0; r < 8; ++r) X[(long)(s0 + r) * G4 + tid] = acc[r];
    }
}

// ---------------------------------------------------------------------------
// Kernel A2: pack recurrent weights into scan-thread order.
// pw[dir][kc][t] (u32x4), t = scan-thread index 0..599 owning col(t) =
// (t&3)*150 + (t>>2). Group kc covers f16 pairs 4kc..4kc+3, pair p =
// (Wr[2p][col], Wr[2p+1][col]); rows >=150 zero-padded (match zeroed h pad).
// Thread-order layout => scan's ds_read_b128 is lane-consecutive 16B:
// each 16-lane quarter-wave covers all 32 banks once (conflict-free).
// ---------------------------------------------------------------------------
__global__ void pack_kernel(const float* __restrict__ Wr_f,
                            const float* __restrict__ Wr_b,
                            unsigned* __restrict__ pw)
{
    const int kc  = blockIdx.x;       // 0..18
    const int dir = blockIdx.y;
    const int t   = threadIdx.x;
    if (t >= G4) return;
    const float* Wr = dir ? Wr_b : Wr_f;
    const int c = (t & 3) * UU + (t >> 2);

    unsigned out[4];
    #pragma unroll
    for (int j = 0; j < 4; ++j) {
        int p  = 4 * kc + j;
        int r0 = 2 * p, r1 = 2 * p + 1;
        float a = (r0 < UU) ? Wr[r0 * G4 + c] : 0.0f;
        float b = (r1 < UU) ? Wr[r1 * G4 + c] : 0.0f;
        HU x; x.h.x = (_Float16)a; x.h.y = (_Float16)b;
        out[j] = x.u;
    }
    u32x4* dst = (u32x4*)(pw + (((long)dir * NGRP + kc) * G4 + t) * 4);
    u32x4 v; v.x = out[0]; v.y = out[1]; v.z = out[2]; v.w = out[3];
    *dst = v;
}

// ---------------------------------------------------------------------------
// Kernel B: LSTM scan. 2 blocks (one per direction), 640 threads (10 waves).
//
// R1-R6 lesson: this toolchain refuses register residency for the weight set
// under every source-level formulation (no pin / budget attrs / pure pin /
// volatile pre-loop pin / volatile in-loop pin) -- it re-streams weights from
// L2 (invisible in FETCH_SIZE, which is HBM-only) at a ~2500 cyc/step floor.
// R7 design is ALLOCATOR-PROOF: no loop-invariant register state. Weights
// stream from LDS every step (that's the intended dataflow, not a demotion):
//   - groups 0..15 (64 pairs, 150 KiB) LDS-resident, filled in the prologue
//   - groups 16..18 (12 pairs, 28.8 KB/step) streamed from L2 (same address
//     every step -> L2-hot; issued at loop top, drains under the dots)
// Per-step: LDS 150KiB/256B = ~600 cyc, VALU ~640 cyc (busiest SIMD, 3 of 10
// waves), L2 ~480 cyc -- three different pipes, overlapped by 10-wave TLP.
//
// Quad gate layout: quad q = tid>>2 owns unit u=q; lane g = tid&3 owns gate
// column col = g*150+u with gate order i,f,g,o. After the dot phase each lane
// holds z_gate(u). Two quad-local shfl_xor's route the activations:
//   act  = (g==2) ? tanh(z) : sigm(z)
//   act2 = shfl_xor(act,2)   // i<->g, f<->o
//   p    = act*act2          // lanes 0,2: sigm(zi)*tanh(zg) = i*g
//   px   = shfl_xor(p,1)     // f-lane receives i*g
//   f-lane: c = sigm(zf)*c + px; h = act2(=sigm(zo)) * tanh(c)
// f-lane is the sole owner/writer of c and h (R3-R6 passed, absmax ~0.16-0.19).
// h broadcast: packed-f16 dwords in LDS, uniform-address ds_read_b128
// (HW broadcast). Double-buffered -> ONE barrier per step.
// ---------------------------------------------------------------------------
__global__ __launch_bounds__(640)
void lstm_scan_kernel(
    const float* __restrict__ Xf, const float* __restrict__ Xb,
    const unsigned* __restrict__ pw,
    float* __restrict__ hidden)
{
    const int dir = blockIdx.x;
    const float* X = dir ? Xb : Xf;
    const u32x4* pwd = (const u32x4*)pw + (long)dir * NGRP * G4;

    const int tid = threadIdx.x;
    const int g   = tid & 3;               // gate: 0=i 1=f 2=g(cell) 3=o
    const int q   = tid >> 2;              // unit index
    const bool active = (q < UU);
    const int u   = active ? q : (UU - 1); // clamp the 10 spare quads in wave 9
    const int col = g * UU + u;
    // thread-order index into pw/wlds; spare threads alias the tid that owns
    // their clamped column: t' = 149*4 + g = 596+g
    const int lcol = active ? tid : (596 + g);

    __shared__ u32x4 wlds[NLDS * G4];                 // 150 KiB weight cache
    __shared__ __align__(16) unsigned hsbuf[2][80];   // double-buffered f16 h (+zero pad)

    // prologue: fill weight cache (coalesced, one-time) and zero h
    for (int e = tid; e < NLDS * G4; e += 640) wlds[e] = pwd[e];
    for (int e = tid; e < 160; e += 640) ((unsigned*)hsbuf)[e] = 0u;

    float c = 0.0f;
    int tt = dir ? (SEQ - 1) : 0;
    const int dt = dir ? -1 : 1;
    float x = X[(long)tt * G4 + col];
    const bool writer = (g == 1) && active;
    float* hout = hidden + dir * UU + u;   // only dereferenced by writer lanes
    const u32x4* wthr = wlds + lcol;               // LDS weights, + kc*600
    const u32x4* gthr = pwd + NLDS * G4 + lcol;    // L2-streamed groups 16..18
    __syncthreads();   // weight cache + h init visibility

    for (int step = 0; step < SEQ; ++step) {
        const int tn = (step < SEQ - 1) ? (tt + dt) : tt;
        // prefetch next x + the 3 streamed weight groups (L2-hot, same addr
        // every step); vmcnt drains overlap the 16 LDS dot-groups below
        float xn = X[(long)tn * G4 + col];
        u32x4 wg0 = gthr[0 * G4];
        u32x4 wg1 = gthr[1 * G4];
        u32x4 wg2 = gthr[2 * G4];

        const u32x4* hb = (const u32x4*)hsbuf[step & 1];

        // 2 accumulators break the dependent dot2 chain
        float aa = x, ab = 0.0f;

        #pragma unroll
        for (int kc = 0; kc < NLDS; ++kc) {
            u32x4 wv = wthr[kc * G4];   // lane-consecutive 16B: conflict-free
            u32x4 hv = hb[kc];          // uniform-address broadcast
            aa = dot2v(wv.x, hv.x, aa); ab = dot2v(wv.y, hv.y, ab);
            aa = dot2v(wv.z, hv.z, aa); ab = dot2v(wv.w, hv.w, ab);
        }
        { u32x4 hv = hb[16];
          aa = dot2v(wg0.x, hv.x, aa); ab = dot2v(wg0.y, hv.y, ab);
          aa = dot2v(wg0.z, hv.z, aa); ab = dot2v(wg0.w, hv.w, ab); }
        { u32x4 hv = hb[17];
          aa = dot2v(wg1.x, hv.x, aa); ab = dot2v(wg1.y, hv.y, ab);
          aa = dot2v(wg1.z, hv.z, aa); ab = dot2v(wg1.w, hv.w, ab); }
        { u32x4 hv = hb[18];
          aa = dot2v(wg2.x, hv.x, aa); ab = dot2v(wg2.y, hv.y, ab);
          aa = dot2v(wg2.z, hv.z, aa); ab = dot2v(wg2.w, hv.w, ab); }

        const float z = aa + ab;          // this lane's gate pre-activation

        // per-lane activation, then quad routing
        float s  = sigm(z);
        float tz = tanh_fast(z);
        float act  = (g == 2) ? tz : s;       // cndmask, no divergence
        float act2 = __shfl_xor(act, 2);      // i<->g, f<->o
        float p    = act * act2;              // lanes 0,2: i*g product
        float px   = __shfl_xor(p, 1);        // f-lane receives i*g
        c = s * c + px;                       // f-lane: sigm(zf)*c + i*g
        float th = tanh_fast(c);
        float hv = act2 * th;                 // f-lane: sigm(zo)*tanh(c)

        if (writer) {
            ((_Float16*)hsbuf[(step & 1) ^ 1])[u] = (_Float16)hv;  // next-step buffer
            hout[(long)tt * H1] = hv;                               // fire-and-forget
        }
        LDS_BARRIER();   // single barrier per step (double-buffer removes the read/write hazard)

        x = xn; tt = tn;
    }
}

// ---------------------------------------------------------------------------
// Kernel C: out = hidden @ W1 + b1   [2048,300]x[300,300]
// ---------------------------------------------------------------------------
__global__ void w1_kernel(const float* __restrict__ hidden,
                          const float* __restrict__ W1,
                          const float* __restrict__ b1,
                          float* __restrict__ outm)
{
    const int s0  = blockIdx.x * 8;
    const int tid = threadIdx.x;
    __shared__ float hl[8][H1];
    for (int e = tid; e < 8 * H1; e += 320)
        hl[e / H1][e - (e / H1) * H1] = hidden[(long)s0 * H1 + e];
    __syncthreads();

    if (tid < H1) {
        float acc[8];
        float bv = b1[tid];
        #pragma unroll
        for (int r = 0; r < 8; ++r) acc[r] = bv;
        for (int k = 0; k < H1; ++k) {
            float wv = W1[k * H1 + tid];
            #pragma unroll
            for (int r = 0; r < 8; ++r) acc[r] = fmaf(hl[r][k], wv, acc[r]);
        }
        #pragma unroll
        for (int r = 0; r < 8; ++r) outm[(long)(s0 + r) * H1 + tid] = acc[r];
    }
}

// ---------------------------------------------------------------------------
// Block reductions for 320-thread blocks (5 waves)
// ---------------------------------------------------------------------------
static __device__ __forceinline__ float4 blockReduce4(float4 v, float* red, int tid)
{
    #pragma unroll
    for (int off = 32; off > 0; off >>= 1) {
        v.x += __shfl_down(v.x, off);
        v.y += __shfl_down(v.y, off);
        v.z += __shfl_down(v.z, off);
        v.w += __shfl_down(v.w, off);
    }
    __syncthreads();
    if ((tid & 63) == 0) {
        int wv = tid >> 6;
        red[wv * 4 + 0] = v.x; red[wv * 4 + 1] = v.y;
        red[wv * 4 + 2] = v.z; red[wv * 4 + 3] = v.w;
    }
    __syncthreads();
    float4 r;
    r.x = red[0]; r.y = red[1]; r.z = red[2]; r.w = red[3];
    #pragma unroll
    for (int wv = 1; wv < 5; ++wv) {
        r.x += red[wv * 4 + 0]; r.y += red[wv * 4 + 1];
        r.z += red[wv * 4 + 2]; r.w += red[wv * 4 + 3];
    }
    return r;
}

static __device__ __forceinline__ float blockReduce1(float v, float* red, int tid)
{
    #pragma unroll
    for (int off = 32; off > 0; off >>= 1) v += __shfl_down(v, off);
    __syncthreads();
    if ((tid & 63) == 0) red[tid >> 6] = v;
    __syncthreads();
    return red[0] + red[1] + red[2] + red[3] + red[4];
}

// ---------------------------------------------------------------------------
// Kernel D: per-position synonym attention; whh[s][d] = c2[s]*h_hat[s][d]
// ---------------------------------------------------------------------------
__global__ void attn_kernel(const int* __restrict__ sentence,
                            const int* __restrict__ syn_idx,
                            const float* __restrict__ emb_mat,
                            const float* __restrict__ outm,
                            const float* __restrict__ hidden,
                            const float* __restrict__ W2,
                            const float* __restrict__ b2,
                            float* __restrict__ whh)
{
    const int s   = blockIdx.x;
    const int t   = s ? (s - 1) : 0;
    const int tid = threadIdx.x;
    __shared__ float red[20];

    const int sent = sentence[s];
    const long i0 = (long)syn_idx[sent * NSYN + 0] * DIM;
    const long i1 = (long)syn_idx[sent * NSYN + 1] * DIM;
    const long i2 = (long)syn_idx[sent * NSYN + 2] * DIM;
    const long i3 = (long)syn_idx[sent * NSYN + 3] * DIM;

    float se0 = 0.f, se1 = 0.f, se2 = 0.f, se3 = 0.f, od = 0.f, hd = 0.f;
    if (tid < DIM) {
        se0 = emb_mat[i0 + tid];
        se1 = emb_mat[i1 + tid];
        se2 = emb_mat[i2 + tid];
        se3 = emb_mat[i3 + tid];
        od  = outm[(long)t * H1 + tid];
        hd  = hidden[(long)t * H1 + tid];
    }

    float4 dots = blockReduce4(make_float4(se0 * od, se1 * od, se2 * od, se3 * od), red, tid);
    float c0 = __expf(dots.x), c1 = __expf(dots.y), c2c = __expf(dots.z), c3 = __expf(dots.w);

    float hh = fmaf(c0, se0, fmaf(c1, se1, fmaf(c2c, se2, fmaf(c3, se3, hd))));

    float w2v = (tid < DIM) ? W2[tid] : 0.f;
    float dot2 = blockReduce1(hh * w2v, red, tid);
    float cc = __expf(tanh_fast(dot2 + b2[0]));

    if (tid < DIM) whh[(long)s * H1 + tid] = cc * hh;
}

// ---------------------------------------------------------------------------
// Kernel E: H[d] = sum_s whh[s][d]
// ---------------------------------------------------------------------------
__global__ void hred_kernel(const float* __restrict__ whh, float* __restrict__ H)
{
    const int d   = blockIdx.x;
    const int tid = threadIdx.x;
    float acc = 0.f;
    for (int s = tid; s < SEQ; s += 256) acc += whh[(long)s * H1 + d];
    #pragma unroll
    for (int off = 32; off > 0; off >>= 1) acc += __shfl_down(acc, off);
    __shared__ float red[4];
    if ((tid & 63) == 0) red[tid >> 6] = acc;
    __syncthreads();
    if (tid == 0) H[d] = red[0] + red[1] + red[2] + red[3];
}

// ---------------------------------------------------------------------------
// Kernel F: logits
// ---------------------------------------------------------------------------
__global__ void logits_kernel(const float* __restrict__ H,
                              const float* __restrict__ We,
                              const float* __restrict__ be,
                              const float* __restrict__ Ws,
                              const float* __restrict__ bs,
                              float* __restrict__ outp)
{
    const int e = threadIdx.x;
    if (e < 9) {
        float acc = (e < 8) ? be[e] : bs[0];
        for (int d = 0; d < H1; ++d) {
            float wv = (e < 8) ? We[d * 8 + e] : Ws[d];
            acc = fmaf(H[d], wv, acc);
        }
        outp[e] = acc;
    }
}

// ---------------------------------------------------------------------------
extern "C" void kernel_launch(void* const* d_in, const int* in_sizes, int n_in,
                              void* d_out, int out_size, void* d_ws, size_t ws_size,
                              hipStream_t stream)
{
    const int* sentence   = (const int*)d_in[0];
    const int* syn_idx    = (const int*)d_in[1];
    const float* emb      = (const float*)d_in[2];
    const float* Wk_f     = (const float*)d_in[3];
    const float* Wr_f     = (const float*)d_in[4];
    const float* b_f      = (const float*)d_in[5];
    const float* Wk_b     = (const float*)d_in[6];
    const float* Wr_b     = (const float*)d_in[7];
    const float* b_b      = (const float*)d_in[8];
    const float* W1       = (const float*)d_in[9];
    const float* b1       = (const float*)d_in[10];
    const float* W2       = (const float*)d_in[11];
    const float* b2       = (const float*)d_in[12];
    const float* We       = (const float*)d_in[13];
    const float* be       = (const float*)d_in[14];
    const float* Ws       = (const float*)d_in[15];
    const float* bs       = (const float*)d_in[16];

    float* ws     = (float*)d_ws;
    float* Xf     = ws;                      // [2048,600]
    float* Xb     = Xf + (long)SEQ * G4;     // [2048,600]
    float* hidden = Xb + (long)SEQ * G4;     // [2048,300]
    float* outm   = hidden + (long)SEQ * H1; // [2048,300]
    float* whh    = outm + (long)SEQ * H1;   // [2048,300]
    float* H      = whh + (long)SEQ * H1;    // [300]
    unsigned* pw  = (unsigned*)(H + H1);     // [2][19][600] u32x4 (16B-aligned offset)

    float* outp = (float*)d_out;

    xpre_kernel<<<dim3(SEQ / 8, 2), 640, 0, stream>>>(sentence, emb, Wk_f, b_f, Wk_b, b_b, Xf, Xb);
    pack_kernel<<<dim3(NGRP, 2), 640, 0, stream>>>(Wr_f, Wr_b, pw);
    lstm_scan_kernel<<<2, 640, 0, stream>>>(Xf, Xb, pw, hidden);
    w1_kernel<<<SEQ / 8, 320, 0, stream>>>(hidden, W1, b1, outm);
    attn_kernel<<<SEQ, 320, 0, stream>>>(sentence, syn_idx, emb, outm, hidden, W2, b2, whh);
    hred_kernel<<<H1, 256, 0, stream>>>(whh, H);
    logits_kernel<<<1, 64, 0, stream>>>(H, We, be, Ws, bs, outp);
}

// Round 8
// 2757.298 us; speedup vs baseline: 1.0786x; 1.0786x over previous
//
#include <hip/hip_runtime.h>
#include <hip/hip_bf16.h>

#define SEQ   2048
#define DIM   300
#define UU    150
#define G4    600   // 4*U
#define H1    300
#define NSYN  4

typedef _Float16 half2v __attribute__((ext_vector_type(2)));
typedef unsigned u32x4 __attribute__((ext_vector_type(4)));
union HU { unsigned u; half2v h; };

static __device__ __forceinline__ float sigm(float x) { return 1.0f / (1.0f + __expf(-x)); }
static __device__ __forceinline__ float tanh_fast(float x) { return 1.0f - 2.0f / (1.0f + __expf(2.0f * x)); }

// HW dot2: acc += w.x*h.x + w.y*h.y (f16 pairs, f32 accumulate). Both operands VGPR.
static __device__ __forceinline__ float dot2v(unsigned w, unsigned h, float acc) {
    asm("v_dot2_f32_f16 %0, %1, %2, %0" : "+v"(acc) : "v"(w), "v"(h));
    return acc;
}

// LDS-only barrier: drains lgkmcnt (LDS) but NOT vmcnt (fire-and-forget global stores).
#define LDS_BARRIER() asm volatile("s_waitcnt lgkmcnt(0)\n\ts_barrier" ::: "memory")

// ---------------------------------------------------------------------------
// Kernel A: emb = embedding[sentence];  Xpre_dir = emb @ Wk_dir + b_dir
// ---------------------------------------------------------------------------
__global__ void xpre_kernel(const int* __restrict__ sentence,
                            const float* __restrict__ emb_mat,
                            const float* __restrict__ Wk_f,
                            const float* __restrict__ b_f,
                            const float* __restrict__ Wk_b,
                            const float* __restrict__ b_b,
                            float* __restrict__ Xf, float* __restrict__ Xb)
{
    const int dir = blockIdx.y;
    const float* Wk = dir ? Wk_b : Wk_f;
    const float* bb = dir ? b_b : b_f;
    float* X = dir ? Xb : Xf;

    const int s0  = blockIdx.x * 8;
    const int tid = threadIdx.x;

    __shared__ int   sids[8];
    __shared__ float embs[8][DIM];

    if (tid < 8) sids[tid] = sentence[s0 + tid];
    __syncthreads();
    for (int e = tid; e < 8 * DIM; e += 640) {
        int r = e / DIM, d = e - r * DIM;
        embs[r][d] = emb_mat[(long)sids[r] * DIM + d];
    }
    __syncthreads();

    if (tid < G4) {
        float acc[8];
        float bv = bb[tid];
        #pragma unroll
        for (int r = 0; r < 8; ++r) acc[r] = bv;
        for (int k = 0; k < DIM; ++k) {
            float wv = Wk[k * G4 + tid];
            #pragma unroll
            for (int r = 0; r < 8; ++r) acc[r] = fmaf(embs[r][k], wv, acc[r]);
        }
        #pragma unroll
        for (int r = 0; r < 8; ++r) X[(long)(s0 + r) * G4 + tid] = acc[r];
    }
}

// ---------------------------------------------------------------------------
// Kernel B: LSTM scan. 2 blocks (one per direction), 256 threads (4 waves).
//
// THE residency recipe (R0 precedent, re-confirmed by R1-R7 failures):
// 256 threads + launch_bounds(256) + amdgpu_waves_per_eu(1,1). At an
// occupancy target of 1 wave/EU the allocator maximizes per-wave registers
// and does NOT rematerialize the 225 loop-invariant weight dwords (R0
// measured VGPR_Count=256, 1990us). Every other geometry/attribute combo
// (R1-R6) remats/demotes them into a ~2200us L2-re-stream floor, and LDS
// weight streaming (R7) is bandwidth-infeasible (ds_read_b128 ~85 B/cyc
// measured -> 2700us).
//
// Delta vs R0 (attacking R0's measured bottleneck, the readlane->SGPR
// hazard path): h is broadcast via uniform-address ds_read_b128 of packed
// f16 pairs (hpair[k] = (h[2k],h[2k+1])) into VGPRs; dots are pure
// VGPR x VGPR v_dot2_f32_f16 (no SGPR writes in the hot path). h chunked
// 4 groups (16 dwords live) to hold total pressure ~250 VGPRs.
// Everything else is R0 verbatim: 3 cols/thread (c0=tid, c1=tid+256,
// c2=tid+512 for tid<88, dummy 599 otherwise), zs[600] in LDS, serial
// tid<150 gate phase, single h buffer with 2 LDS barriers/step.
// ---------------------------------------------------------------------------
#define REP75(F) \
  F(0) F(1) F(2) F(3) F(4) F(5) F(6) F(7) F(8) F(9) \
  F(10) F(11) F(12) F(13) F(14) F(15) F(16) F(17) F(18) F(19) \
  F(20) F(21) F(22) F(23) F(24) F(25) F(26) F(27) F(28) F(29) \
  F(30) F(31) F(32) F(33) F(34) F(35) F(36) F(37) F(38) F(39) \
  F(40) F(41) F(42) F(43) F(44) F(45) F(46) F(47) F(48) F(49) \
  F(50) F(51) F(52) F(53) F(54) F(55) F(56) F(57) F(58) F(59) \
  F(60) F(61) F(62) F(63) F(64) F(65) F(66) F(67) F(68) F(69) \
  F(70) F(71) F(72) F(73) F(74)

static __device__ __forceinline__ unsigned packpair(const float* __restrict__ Wr, int c, int k) {
    HU x;
    x.h.x = (_Float16)Wr[(2 * k) * G4 + c];
    x.h.y = (_Float16)Wr[(2 * k + 1) * G4 + c];
    return x.u;
}

__global__ __launch_bounds__(256) __attribute__((amdgpu_waves_per_eu(1, 1)))
void lstm_scan_kernel(
    const float* __restrict__ Xf, const float* __restrict__ Xb,
    const float* __restrict__ Wr_f, const float* __restrict__ Wr_b,
    float* __restrict__ hidden)
{
    const int dir = blockIdx.x;
    const float* X  = dir ? Xb : Xf;
    const float* Wr = dir ? Wr_b : Wr_f;
    const int tid  = threadIdx.x;

    __shared__ float zs[G4];
    __shared__ __align__(16) unsigned hpair[80];   // f16 pairs; dwords 75..79 stay 0

    const int c0 = tid;
    const int c1 = tid + 256;
    const bool has2 = (tid < 88);
    const int c2 = has2 ? (tid + 512) : 599;

    // --- f16-packed weights in named registers (225 dwords) ---
#define WDECL(k) unsigned wA_##k, wB_##k, wC_##k;
    REP75(WDECL)
#undef WDECL
#define WLOAD(k) wA_##k = packpair(Wr, c0, k); wB_##k = packpair(Wr, c1, k); wC_##k = packpair(Wr, c2, k);
    REP75(WLOAD)
#undef WLOAD

    if (tid < 80) hpair[tid] = 0u;   // h = 0 (incl. zero pad for pairs 75..79)

    float c = 0.0f;
    int t = dir ? (SEQ - 1) : 0;
    const int dt = dir ? -1 : 1;
    __syncthreads();   // init visibility (once, outside the loop)

    const u32x4* hb = (const u32x4*)hpair;

    for (int step = 0; step < SEQ; ++step) {
        // x issued at loop top, consumed ~450 cyc later at the z write:
        // vmcnt wait fully overlaps the dot phase (no xn double-buffer needed)
        float x0 = X[(long)t * G4 + c0];
        float x1 = X[(long)t * G4 + c1];
        float x2 = X[(long)t * G4 + c2];

        float a0 = 0.0f, a1 = 0.0f, a2 = 0.0f;

        // uniform-address broadcast reads, 4 groups (16 dwords) live at a time
        u32x4 h0 = hb[0], h1 = hb[1], h2 = hb[2], h3 = hb[3];

#define DOTG(k0,k1,k2,k3,hv) \
        a0 = dot2v(wA_##k0, hv.x, a0); a1 = dot2v(wB_##k0, hv.x, a1); a2 = dot2v(wC_##k0, hv.x, a2); \
        a0 = dot2v(wA_##k1, hv.y, a0); a1 = dot2v(wB_##k1, hv.y, a1); a2 = dot2v(wC_##k1, hv.y, a2); \
        a0 = dot2v(wA_##k2, hv.z, a0); a1 = dot2v(wB_##k2, hv.z, a1); a2 = dot2v(wC_##k2, hv.z, a2); \
        a0 = dot2v(wA_##k3, hv.w, a0); a1 = dot2v(wB_##k3, hv.w, a1); a2 = dot2v(wC_##k3, hv.w, a2);

        DOTG(0,1,2,3,h0)    DOTG(4,5,6,7,h1)    DOTG(8,9,10,11,h2)   DOTG(12,13,14,15,h3)
        h0 = hb[4]; h1 = hb[5]; h2 = hb[6]; h3 = hb[7];
        DOTG(16,17,18,19,h0) DOTG(20,21,22,23,h1) DOTG(24,25,26,27,h2) DOTG(28,29,30,31,h3)
        h0 = hb[8]; h1 = hb[9]; h2 = hb[10]; h3 = hb[11];
        DOTG(32,33,34,35,h0) DOTG(36,37,38,39,h1) DOTG(40,41,42,43,h2) DOTG(44,45,46,47,h3)
        h0 = hb[12]; h1 = hb[13]; h2 = hb[14]; h3 = hb[15];
        DOTG(48,49,50,51,h0) DOTG(52,53,54,55,h1) DOTG(56,57,58,59,h2) DOTG(60,61,62,63,h3)
        h0 = hb[16]; h1 = hb[17]; h2 = hb[18];
        DOTG(64,65,66,67,h0) DOTG(68,69,70,71,h1)
        // remainder pairs 72..74 (h2.w pairs with the zeroed pad dword 75)
        a0 = dot2v(wA_72, h2.x, a0); a1 = dot2v(wB_72, h2.x, a1); a2 = dot2v(wC_72, h2.x, a2);
        a0 = dot2v(wA_73, h2.y, a0); a1 = dot2v(wB_73, h2.y, a1); a2 = dot2v(wC_73, h2.y, a2);
        a0 = dot2v(wA_74, h2.z, a0); a1 = dot2v(wB_74, h2.z, a1); a2 = dot2v(wC_74, h2.z, a2);
#undef DOTG

        zs[c0] = a0 + x0;
        zs[c1] = a1 + x1;
        if (has2) zs[c2] = a2 + x2;
        LDS_BARRIER();   // drains all waves' h reads + z writes

        if (tid < UU) {
            float zi = zs[tid], zf = zs[UU + tid], zg = zs[2 * UU + tid], zo = zs[3 * UU + tid];
            float ig = sigm(zi);
            float fg = sigm(zf);
            float gg = tanh_fast(zg);
            float og = sigm(zo);
            c = fg * c + ig * gg;
            float hv = og * tanh_fast(c);
            ((_Float16*)hpair)[tid] = (_Float16)hv;
            hidden[(long)t * H1 + dir * UU + tid] = hv;   // fire-and-forget
        }
        LDS_BARRIER();   // h visible before next step's broadcast reads

        t += dt;
    }
}

// ---------------------------------------------------------------------------
// Kernel C: out = hidden @ W1 + b1   [2048,300]x[300,300]
// ---------------------------------------------------------------------------
__global__ void w1_kernel(const float* __restrict__ hidden,
                          const float* __restrict__ W1,
                          const float* __restrict__ b1,
                          float* __restrict__ outm)
{
    const int s0  = blockIdx.x * 8;
    const int tid = threadIdx.x;
    __shared__ float hl[8][H1];
    for (int e = tid; e < 8 * H1; e += 320)
        hl[e / H1][e - (e / H1) * H1] = hidden[(long)s0 * H1 + e];
    __syncthreads();

    if (tid < H1) {
        float acc[8];
        float bv = b1[tid];
        #pragma unroll
        for (int r = 0; r < 8; ++r) acc[r] = bv;
        for (int k = 0; k < H1; ++k) {
            float wv = W1[k * H1 + tid];
            #pragma unroll
            for (int r = 0; r < 8; ++r) acc[r] = fmaf(hl[r][k], wv, acc[r]);
        }
        #pragma unroll
        for (int r = 0; r < 8; ++r) outm[(long)(s0 + r) * H1 + tid] = acc[r];
    }
}

// ---------------------------------------------------------------------------
// Block reductions for 320-thread blocks (5 waves)
// ---------------------------------------------------------------------------
static __device__ __forceinline__ float4 blockReduce4(float4 v, float* red, int tid)
{
    #pragma unroll
    for (int off = 32; off > 0; off >>= 1) {
        v.x += __shfl_down(v.x, off);
        v.y += __shfl_down(v.y, off);
        v.z += __shfl_down(v.z, off);
        v.w += __shfl_down(v.w, off);
    }
    __syncthreads();
    if ((tid & 63) == 0) {
        int wv = tid >> 6;
        red[wv * 4 + 0] = v.x; red[wv * 4 + 1] = v.y;
        red[wv * 4 + 2] = v.z; red[wv * 4 + 3] = v.w;
    }
    __syncthreads();
    float4 r;
    r.x = red[0]; r.y = red[1]; r.z = red[2]; r.w = red[3];
    #pragma unroll
    for (int wv = 1; wv < 5; ++wv) {
        r.x += red[wv * 4 + 0]; r.y += red[wv * 4 + 1];
        r.z += red[wv * 4 + 2]; r.w += red[wv * 4 + 3];
    }
    return r;
}

static __device__ __forceinline__ float blockReduce1(float v, float* red, int tid)
{
    #pragma unroll
    for (int off = 32; off > 0; off >>= 1) v += __shfl_down(v, off);
    __syncthreads();
    if ((tid & 63) == 0) red[tid >> 6] = v;
    __syncthreads();
    return red[0] + red[1] + red[2] + red[3] + red[4];
}

// ---------------------------------------------------------------------------
// Kernel D: per-position synonym attention; whh[s][d] = c2[s]*h_hat[s][d]
// ---------------------------------------------------------------------------
__global__ void attn_kernel(const int* __restrict__ sentence,
                            const int* __restrict__ syn_idx,
                            const float* __restrict__ emb_mat,
                            const float* __restrict__ outm,
                            const float* __restrict__ hidden,
                            const float* __restrict__ W2,
                            const float* __restrict__ b2,
                            float* __restrict__ whh)
{
    const int s   = blockIdx.x;
    const int t   = s ? (s - 1) : 0;
    const int tid = threadIdx.x;
    __shared__ float red[20];

    const int sent = sentence[s];
    const long i0 = (long)syn_idx[sent * NSYN + 0] * DIM;
    const long i1 = (long)syn_idx[sent * NSYN + 1] * DIM;
    const long i2 = (long)syn_idx[sent * NSYN + 2] * DIM;
    const long i3 = (long)syn_idx[sent * NSYN + 3] * DIM;

    float se0 = 0.f, se1 = 0.f, se2 = 0.f, se3 = 0.f, od = 0.f, hd = 0.f;
    if (tid < DIM) {
        se0 = emb_mat[i0 + tid];
        se1 = emb_mat[i1 + tid];
        se2 = emb_mat[i2 + tid];
        se3 = emb_mat[i3 + tid];
        od  = outm[(long)t * H1 + tid];
        hd  = hidden[(long)t * H1 + tid];
    }

    float4 dots = blockReduce4(make_float4(se0 * od, se1 * od, se2 * od, se3 * od), red, tid);
    float c0 = __expf(dots.x), c1 = __expf(dots.y), c2c = __expf(dots.z), c3 = __expf(dots.w);

    float hh = fmaf(c0, se0, fmaf(c1, se1, fmaf(c2c, se2, fmaf(c3, se3, hd))));

    float w2v = (tid < DIM) ? W2[tid] : 0.f;
    float dot2 = blockReduce1(hh * w2v, red, tid);
    float cc = __expf(tanh_fast(dot2 + b2[0]));

    if (tid < DIM) whh[(long)s * H1 + tid] = cc * hh;
}

// ---------------------------------------------------------------------------
// Kernel E: H[d] = sum_s whh[s][d]
// ---------------------------------------------------------------------------
__global__ void hred_kernel(const float* __restrict__ whh, float* __restrict__ H)
{
    const int d   = blockIdx.x;
    const int tid = threadIdx.x;
    float acc = 0.f;
    for (int s = tid; s < SEQ; s += 256) acc += whh[(long)s * H1 + d];
    #pragma unroll
    for (int off = 32; off > 0; off >>= 1) acc += __shfl_down(acc, off);
    __shared__ float red[4];
    if ((tid & 63) == 0) red[tid >> 6] = acc;
    __syncthreads();
    if (tid == 0) H[d] = red[0] + red[1] + red[2] + red[3];
}

// ---------------------------------------------------------------------------
// Kernel F: logits
// ---------------------------------------------------------------------------
__global__ void logits_kernel(const float* __restrict__ H,
                              const float* __restrict__ We,
                              const float* __restrict__ be,
                              const float* __restrict__ Ws,
                              const float* __restrict__ bs,
                              float* __restrict__ outp)
{
    const int e = threadIdx.x;
    if (e < 9) {
        float acc = (e < 8) ? be[e] : bs[0];
        for (int d = 0; d < H1; ++d) {
            float wv = (e < 8) ? We[d * 8 + e] : Ws[d];
            acc = fmaf(H[d], wv, acc);
        }
        outp[e] = acc;
    }
}

// ---------------------------------------------------------------------------
extern "C" void kernel_launch(void* const* d_in, const int* in_sizes, int n_in,
                              void* d_out, int out_size, void* d_ws, size_t ws_size,
                              hipStream_t stream)
{
    const int* sentence   = (const int*)d_in[0];
    const int* syn_idx    = (const int*)d_in[1];
    const float* emb      = (const float*)d_in[2];
    const float* Wk_f     = (const float*)d_in[3];
    const float* Wr_f     = (const float*)d_in[4];
    const float* b_f      = (const float*)d_in[5];
    const float* Wk_b     = (const float*)d_in[6];
    const float* Wr_b     = (const float*)d_in[7];
    const float* b_b      = (const float*)d_in[8];
    const float* W1       = (const float*)d_in[9];
    const float* b1       = (const float*)d_in[10];
    const float* W2       = (const float*)d_in[11];
    const float* b2       = (const float*)d_in[12];
    const float* We       = (const float*)d_in[13];
    const float* be       = (const float*)d_in[14];
    const float* Ws       = (const float*)d_in[15];
    const float* bs       = (const float*)d_in[16];

    float* ws     = (float*)d_ws;
    float* Xf     = ws;                      // [2048,600]
    float* Xb     = Xf + (long)SEQ * G4;     // [2048,600]
    float* hidden = Xb + (long)SEQ * G4;     // [2048,300]
    float* outm   = hidden + (long)SEQ * H1; // [2048,300]
    float* whh    = outm + (long)SEQ * H1;   // [2048,300]
    float* H      = whh + (long)SEQ * H1;    // [300]

    float* outp = (float*)d_out;

    xpre_kernel<<<dim3(SEQ / 8, 2), 640, 0, stream>>>(sentence, emb, Wk_f, b_f, Wk_b, b_b, Xf, Xb);
    lstm_scan_kernel<<<2, 256, 0, stream>>>(Xf, Xb, Wr_f, Wr_b, hidden);
    w1_kernel<<<SEQ / 8, 320, 0, stream>>>(hidden, W1, b1, outm);
    attn_kernel<<<SEQ, 320, 0, stream>>>(sentence, syn_idx, emb, outm, hidden, W2, b2, whh);
    hred_kernel<<<H1, 256, 0, stream>>>(whh, H);
    logits_kernel<<<1, 64, 0, stream>>>(H, We, be, Ws, bs, outp);
}